// Round 3
// baseline (1228.313 us; speedup 1.0000x reference)
//
#include <hip/hip_runtime.h>
#include <math.h>

#define NN_ 1024
#define DOUT_ 2112
#define NOUT_ 384
#define G_ 4
#define MT_ 32
#define NTILES_ 32

// ---------------- K1: yraw[1024][1152] = in1 @ [wq|wkv|wqp|wkvp] + bias ----------------
__global__ __launch_bounds__(256) void k_gemm1(
    const float* __restrict__ in1,
    const float* __restrict__ wq, const float* __restrict__ bq,
    const float* __restrict__ wkv, const float* __restrict__ bkv,
    const float* __restrict__ wqp, const float* __restrict__ bqp,
    const float* __restrict__ wkvp, const float* __restrict__ bkvp,
    float* __restrict__ yraw)
{
    __shared__ float a_l[64 * 36];
    __shared__ float b_l[32 * 68];
    const int t = threadIdx.x;
    const int m0 = blockIdx.x * 64, j0 = blockIdx.y * 64;
    const int tx = t & 15, ty = t >> 4;
    float acc[4][4] = {};
    for (int k0 = 0; k0 < 384; k0 += 32) {
        #pragma unroll
        for (int e = 0; e < 2; ++e) {
            int idx = t + 256 * e;
            int r = idx >> 3, c4 = (idx & 7) * 4;
            *(float4*)&a_l[r * 36 + c4] = *(const float4*)&in1[(size_t)(m0 + r) * 384 + k0 + c4];
        }
        #pragma unroll
        for (int e = 0; e < 2; ++e) {
            int idx = t + 256 * e;
            int r = idx >> 4, c4 = (idx & 15) * 4;
            int j = j0 + c4;
            const float* w; int ncol, jj;
            if (j < 192)      { w = wq;   ncol = 192; jj = j; }
            else if (j < 576) { w = wkv;  ncol = 384; jj = j - 192; }
            else if (j < 720) { w = wqp;  ncol = 144; jj = j - 576; }
            else              { w = wkvp; ncol = 432; jj = j - 720; }
            *(float4*)&b_l[r * 68 + c4] = *(const float4*)&w[(size_t)(k0 + r) * ncol + jj];
        }
        __syncthreads();
        #pragma unroll 8
        for (int k = 0; k < 32; ++k) {
            float4 bv = *(const float4*)&b_l[k * 68 + tx * 4];
            #pragma unroll
            for (int i = 0; i < 4; ++i) {
                float av = a_l[(ty * 4 + i) * 36 + k];
                acc[i][0] += av * bv.x; acc[i][1] += av * bv.y;
                acc[i][2] += av * bv.z; acc[i][3] += av * bv.w;
            }
        }
        __syncthreads();
    }
    int j = j0 + tx * 4;
    float4 bias;
    {
        const float* b; int jj;
        if (j < 192)      { b = bq;   jj = j; }
        else if (j < 576) { b = bkv;  jj = j - 192; }
        else if (j < 720) { b = bqp;  jj = j - 576; }
        else              { b = bkvp; jj = j - 720; }
        bias = *(const float4*)&b[jj];
    }
    #pragma unroll
    for (int i = 0; i < 4; ++i) {
        float4 o;
        o.x = acc[i][0] + bias.x; o.y = acc[i][1] + bias.y;
        o.z = acc[i][2] + bias.z; o.w = acc[i][3] + bias.w;
        *(float4*)&yraw[(size_t)(m0 + ty * 4 + i) * 1152 + j] = o;
    }
}

// ---------------- K2: rotations + packing ----------------
// kpack[n][352]: [0:192 ks(h*16+s)] [192:336 kp(a*48+h*4+p)] [336:348 sk(h)]
// vpack[n][480]: [0:192 vs(h*16+s)] [192:480 vp(a*96+h*8+p)]
__global__ __launch_bounds__(256) void k_rot(
    const float* __restrict__ yraw, const float* __restrict__ rotm, const float* __restrict__ trans,
    float* __restrict__ qp_arr, float* __restrict__ kpack, float* __restrict__ vpack,
    float* __restrict__ sq_arr)
{
    __shared__ float rt_l[4][12];
    const int t = threadIdx.x;
    const int n0 = blockIdx.x * 4;
    if (t < 48) {
        int n_ = t / 12, i = t % 12;
        rt_l[n_][i] = (i < 9) ? rotm[(n0 + n_) * 9 + i] : trans[(n0 + n_) * 3 + (i - 9)];
    }
    __syncthreads();
    const int n_ = t >> 6, l = t & 63;
    const int n = n0 + n_;
    const float* y = yraw + (size_t)n * 1152;
    const float* R = rt_l[n_];
    #pragma unroll
    for (int jj = 0; jj < 9; ++jj) {
        int o = l + 64 * jj;
        if (o < 144) {
            int a = o / 48, kk = o % 48;
            float v = R[9 + a] + R[a*3+0] * y[576 + kk] + R[a*3+1] * y[576 + 48 + kk] + R[a*3+2] * y[576 + 96 + kk];
            qp_arr[(size_t)n * 144 + o] = v;
        } else if (o < 288) {
            int o2 = o - 144;
            int a = o2 / 48, r2 = o2 % 48;
            int kk = (r2 >> 2) * 12 + (r2 & 3);
            float v = R[9 + a] + R[a*3+0] * y[720 + kk] + R[a*3+1] * y[720 + 144 + kk] + R[a*3+2] * y[720 + 288 + kk];
            kpack[(size_t)n * 352 + 192 + o2] = v;
        } else {
            int o3 = o - 288;
            int a = o3 / 96, r2 = o3 % 96;
            int kk = (r2 >> 3) * 12 + 4 + (r2 & 7);
            float v = R[9 + a] + R[a*3+0] * y[720 + kk] + R[a*3+1] * y[720 + 144 + kk] + R[a*3+2] * y[720 + 288 + kk];
            vpack[(size_t)n * 480 + 192 + o3] = v;
        }
    }
    #pragma unroll
    for (int jj = 0; jj < 3; ++jj) {
        int o = l + 64 * jj;  // 0..191
        int h = o >> 4, r2 = o & 15;
        kpack[(size_t)n * 352 + o] = y[192 + h * 32 + r2];
        vpack[(size_t)n * 480 + o] = y[192 + h * 32 + 16 + r2];
    }
    if (l < 24) {
        int which = l / 12, h = l % 12;
        int base = (which == 0) ? 576 : 720;
        int stride = (which == 0) ? 48 : 144;
        float s = 0.f;
        #pragma unroll
        for (int a = 0; a < 3; ++a) {
            #pragma unroll
            for (int p = 0; p < 4; ++p) {
                int kk = (which == 0) ? (h * 4 + p) : (h * 12 + p);
                float v = R[9 + a] + R[a*3+0] * y[base + kk] + R[a*3+1] * y[base + stride + kk] + R[a*3+2] * y[base + 2 * stride + kk];
                s += v * v;
            }
        }
        if (which == 0) sq_arr[(size_t)n * 12 + h] = s;
        else            kpack[(size_t)n * 352 + 336 + h] = s;
    }
}

// ---------------- K3: fused flash IPA, 4 query rows per block, 1024 threads ----------------
__global__ __launch_bounds__(1024) void k_attn3(
    const float* __restrict__ x2d, const float* __restrict__ mask,
    const float* __restrict__ w2d, const float* __restrict__ b2d, const float* __restrict__ tpw,
    const float* __restrict__ yraw, const float* __restrict__ qp_arr,
    const float* __restrict__ kpack, const float* __restrict__ vpack,
    const float* __restrict__ sq_arr, const float* __restrict__ rotm,
    const float* __restrict__ trans,
    float* __restrict__ fin)
{
    __shared__ float K_l[MT_][356];          // 45.6 KB
    __shared__ float x_l[G_][MT_][132];      // 67.6 KB
    __shared__ float tl[G_][12][36];         // 6.9 KB
    __shared__ float at2_l[G_][MT_][12];     // 6.1 KB
    __shared__ float w2_l[12][128];          // 6.1 KB
    __shared__ float qs_l[G_][192];
    __shared__ float qp_l[G_][144];
    __shared__ float sq_l[G_][12];
    __shared__ float rt_l[G_][12];
    __shared__ float pw_l[12], b2_l[12];
    __shared__ float maskn_l[G_];
    __shared__ float rmax_l[G_][12], rsum_l[G_][12], alph_l[G_][12];
    __shared__ float pg_l[G_][288];

    const int t = threadIdx.x;
    const int n0 = blockIdx.x * G_;

    // ---- thread mappings ----
    const int sn = t >> 8;             // stage: n
    const int sm = (t >> 3) & 31;      // stage: m
    const int k8 = t & 7;              // stage: k-octant (16 c each)
    const int rep = t >> 9;            // logits: n-pair select
    const int hx  = (t >> 5) & 15;     // logits: h (active <12)
    const int m2  = t & 31;            // logits: m
    const int cq  = t & 31;            // res2d: c-quad
    const int hg5 = (t >> 5) & 3;      // res2d: h-trio
    const int n5  = (t >> 7) & 3;      // res2d: n
    const int ms  = t >> 9;            // res2d: m-half
    const int hb  = hg5 * 3;
    const int jF  = t >> 1;            // resF: j (active t<960)
    const int npF = t & 1;             // resF: n-pair
    const int hF  = (jF < 192) ? (jF >> 4) : (((jF - 192) % 96) >> 3);

    float accR[12];
    #pragma unroll
    for (int e = 0; e < 12; ++e) accR[e] = 0.f;
    float accF0 = 0.f, accF1 = 0.f;
    float4 xpf[4];
    float4 kpf[3];

    // ---- prologue ----
    for (int i = t; i < 1536; i += 1024) { int c = i / 12, h = i % 12; w2_l[h][c] = w2d[i]; }
    if (t < 768) { int nl = t / 192, r = t % 192; qs_l[nl][r] = yraw[(size_t)(n0 + nl) * 1152 + r]; }
    if (t < 576) { int nl = t / 144, r = t % 144; qp_l[nl][r] = qp_arr[(size_t)(n0 + nl) * 144 + r]; }
    if (t < 48)  { int nl = t / 12, r = t % 12; sq_l[nl][r] = sq_arr[(size_t)(n0 + nl) * 12 + r]; }
    if (t >= 64 && t < 112) {
        int i = t - 64, nl = i / 12, r = i % 12;
        rt_l[nl][r] = (r < 9) ? rotm[(n0 + nl) * 9 + r] : trans[(n0 + nl) * 3 + (r - 9)];
    }
    if (t >= 128 && t < 140) pw_l[t - 128] = 0.13608276348795434f * log1pf(__expf(tpw[t - 128]));
    if (t >= 160 && t < 172) b2_l[t - 160] = b2d[t - 160];
    if (t >= 192 && t < 196) maskn_l[t - 192] = mask[n0 + (t - 192)];
    if (t >= 224 && t < 272) { int i = t - 224; rmax_l[i / 12][i % 12] = -3.0e38f; }
    if (t >= 288 && t < 336) { int i = t - 288; rsum_l[i / 12][i % 12] = 0.f; }

    // initial prefetch (tile 0)
    #pragma unroll
    for (int f = 0; f < 4; ++f)
        xpf[f] = *(const float4*)&x2d[((size_t)(n0 + sn) * NN_ + sm) * 128 + k8 * 16 + f * 4];
    kpf[0] = *(const float4*)&kpack[(size_t)t * 4];
    kpf[1] = *(const float4*)&kpack[(size_t)(t + 1024) * 4];
    { int fi = (t < 768) ? (t + 2048) : 0; kpf[2] = *(const float4*)&kpack[(size_t)fi * 4]; }
    __syncthreads();

    for (int mt = 0; mt < NTILES_; ++mt) {
        const int m0 = mt * MT_;
        // ================= P1: commit prefetch to LDS + att2d partials =================
        *(float4*)&K_l[t / 88][(t % 88) * 4] = kpf[0];
        *(float4*)&K_l[(t + 1024) / 88][((t + 1024) % 88) * 4] = kpf[1];
        if (t < 768) *(float4*)&K_l[(t + 2048) / 88][((t + 2048) % 88) * 4] = kpf[2];
        #pragma unroll
        for (int f = 0; f < 4; ++f)
            *(float4*)&x_l[sn][sm][k8 * 16 + f * 4] = xpf[f];
        float at2[12];
        #pragma unroll
        for (int h = 0; h < 12; ++h) {
            float s = 0.f;
            #pragma unroll
            for (int f = 0; f < 4; ++f) {
                float4 wv = *(const float4*)&w2_l[h][k8 * 16 + f * 4];
                s += xpf[f].x * wv.x + xpf[f].y * wv.y + xpf[f].z * wv.z + xpf[f].w * wv.w;
            }
            at2[h] = s;
        }
        #pragma unroll
        for (int d = 1; d <= 4; d <<= 1) {
            #pragma unroll
            for (int h = 0; h < 12; ++h) at2[h] += __shfl_xor(at2[h], d);
        }
        if (k8 == 0) {
            #pragma unroll
            for (int h = 0; h < 12; ++h) at2_l[sn][sm][h] = at2[h];
        }
        __syncthreads();

        // ================= P2: logits + online softmax (wave-internal) =================
        if (hx < 12) {
            const int h = hx;
            const float* kr = &K_l[m2][0];
            float4 ksA = *(const float4*)&kr[h * 16 + 0];
            float4 ksB = *(const float4*)&kr[h * 16 + 4];
            float4 ksC = *(const float4*)&kr[h * 16 + 8];
            float4 ksD = *(const float4*)&kr[h * 16 + 12];
            float4 kpA = *(const float4*)&kr[192 + h * 4];
            float4 kpB = *(const float4*)&kr[192 + 48 + h * 4];
            float4 kpC = *(const float4*)&kr[192 + 96 + h * 4];
            float skm = kr[336 + h];
            float mkm = mask[m0 + m2];
            float pwh = pw_l[h];
            #pragma unroll
            for (int nn = 0; nn < 2; ++nn) {
                const int n = rep * 2 + nn;
                const float4* qsn = (const float4*)&qs_l[n][h * 16];
                float dqs = qsn[0].x*ksA.x + qsn[0].y*ksA.y + qsn[0].z*ksA.z + qsn[0].w*ksA.w
                          + qsn[1].x*ksB.x + qsn[1].y*ksB.y + qsn[1].z*ksB.z + qsn[1].w*ksB.w
                          + qsn[2].x*ksC.x + qsn[2].y*ksC.y + qsn[2].z*ksC.z + qsn[2].w*ksC.w
                          + qsn[3].x*ksD.x + qsn[3].y*ksD.y + qsn[3].z*ksD.z + qsn[3].w*ksD.w;
                float4 qA = *(const float4*)&qp_l[n][h * 4];
                float4 qB = *(const float4*)&qp_l[n][48 + h * 4];
                float4 qC = *(const float4*)&qp_l[n][96 + h * 4];
                float qk = qA.x*kpA.x + qA.y*kpA.y + qA.z*kpA.z + qA.w*kpA.w
                         + qB.x*kpB.x + qB.y*kpB.y + qB.z*kpB.z + qB.w*kpB.w
                         + qC.x*kpC.x + qC.y*kpC.y + qC.z*kpC.z + qC.w*kpC.w;
                float lg = 0.14433756729740643f * dqs
                         + pwh * qk - 0.5f * pwh * (sq_l[n][h] + skm)
                         + 0.57735026918962576f * (at2_l[n][m2][h] + b2_l[h])
                         - 100000.0f * (1.0f - maskn_l[n] * mkm);
                float tm = lg;
                tm = fmaxf(tm, __shfl_xor(tm, 1));
                tm = fmaxf(tm, __shfl_xor(tm, 2));
                tm = fmaxf(tm, __shfl_xor(tm, 4));
                tm = fmaxf(tm, __shfl_xor(tm, 8));
                tm = fmaxf(tm, __shfl_xor(tm, 16));
                float om = rmax_l[n][h];
                float nm = fmaxf(om, tm);
                float p = __expf(lg - nm);
                tl[n][h][m2] = p;
                float ps = p;
                ps += __shfl_xor(ps, 1);
                ps += __shfl_xor(ps, 2);
                ps += __shfl_xor(ps, 4);
                ps += __shfl_xor(ps, 8);
                ps += __shfl_xor(ps, 16);
                if (m2 == 0) {
                    float al = __expf(om - nm);
                    rmax_l[n][h] = nm;
                    alph_l[n][h] = al;
                    rsum_l[n][h] = rsum_l[n][h] * al + ps;
                }
            }
        }
        __syncthreads();

        // ================= P5: prefetch-next + rescale + res2d; P6: resF =================
        {
            int m1 = (mt + 1 == NTILES_) ? 0 : (m0 + MT_);
            #pragma unroll
            for (int f = 0; f < 4; ++f)
                xpf[f] = *(const float4*)&x2d[((size_t)(n0 + sn) * NN_ + m1 + sm) * 128 + k8 * 16 + f * 4];
            kpf[0] = *(const float4*)&kpack[(size_t)m1 * 352 + (size_t)t * 4];
            kpf[1] = *(const float4*)&kpack[(size_t)m1 * 352 + (size_t)(t + 1024) * 4];
            int fi = (t < 768) ? (t + 2048) : 0;
            kpf[2] = *(const float4*)&kpack[(size_t)m1 * 352 + (size_t)fi * 4];
        }
        {
            float alv[3];
            #pragma unroll
            for (int e = 0; e < 3; ++e) alv[e] = alph_l[n5][hb + e];
            #pragma unroll
            for (int e = 0; e < 12; ++e) accR[e] *= alv[e >> 2];
            #pragma unroll
            for (int mm = 0; mm < 16; mm += 4) {
                const int mB = ms * 16 + mm;
                float4 p0 = *(const float4*)&tl[n5][hb + 0][mB];
                float4 p1 = *(const float4*)&tl[n5][hb + 1][mB];
                float4 p2 = *(const float4*)&tl[n5][hb + 2][mB];
                float pa0[4] = {p0.x, p0.y, p0.z, p0.w};
                float pa1[4] = {p1.x, p1.y, p1.z, p1.w};
                float pa2[4] = {p2.x, p2.y, p2.z, p2.w};
                #pragma unroll
                for (int q = 0; q < 4; ++q) {
                    float4 xv = *(const float4*)&x_l[n5][mB + q][cq * 4];
                    accR[0] += pa0[q] * xv.x; accR[1]  += pa0[q] * xv.y; accR[2]  += pa0[q] * xv.z; accR[3]  += pa0[q] * xv.w;
                    accR[4] += pa1[q] * xv.x; accR[5]  += pa1[q] * xv.y; accR[6]  += pa1[q] * xv.z; accR[7]  += pa1[q] * xv.w;
                    accR[8] += pa2[q] * xv.x; accR[9]  += pa2[q] * xv.y; accR[10] += pa2[q] * xv.z; accR[11] += pa2[q] * xv.w;
                }
            }
        }
        if (t < 960) {
            const int nA = npF * 2, nB = nA + 1;
            accF0 *= alph_l[nA][hF];
            accF1 *= alph_l[nB][hF];
            const float* vb = vpack + (size_t)m0 * 480 + jF;
            #pragma unroll 2
            for (int mm = 0; mm < 32; mm += 4) {
                float4 pA = *(const float4*)&tl[nA][hF][mm];
                float4 pB = *(const float4*)&tl[nB][hF][mm];
                float v0 = vb[(size_t)(mm + 0) * 480];
                float v1 = vb[(size_t)(mm + 1) * 480];
                float v2 = vb[(size_t)(mm + 2) * 480];
                float v3 = vb[(size_t)(mm + 3) * 480];
                accF0 += pA.x * v0 + pA.y * v1 + pA.z * v2 + pA.w * v3;
                accF1 += pB.x * v0 + pB.y * v1 + pB.z * v2 + pB.w * v3;
            }
        }
        __syncthreads();
    }

    // ================= epilogue =================
    float* red = &K_l[0][0];
    if (ms == 1) {
        #pragma unroll
        for (int e = 0; e < 12; ++e) red[(t & 511) * 12 + e] = accR[e];
    }
    __syncthreads();
    if (ms == 0) {
        float inv[3];
        #pragma unroll
        for (int e = 0; e < 3; ++e) inv[e] = 1.f / rsum_l[n5][hb + e];
        #pragma unroll
        for (int e = 0; e < 12; ++e) {
            float v = (accR[e] + red[(t & 511) * 12 + e]) * inv[e >> 2];
            fin[(size_t)(n0 + n5) * DOUT_ + 576 + (size_t)(hb + (e >> 2)) * 128 + cq * 4 + (e & 3)] = v;
        }
    }
    if (t < 960) {
        const int nA = npF * 2, nB = nA + 1;
        float vA = accF0 / rsum_l[nA][hF];
        float vB = accF1 / rsum_l[nB][hF];
        if (jF < 192) {
            fin[(size_t)(n0 + nA) * DOUT_ + jF] = vA;
            fin[(size_t)(n0 + nB) * DOUT_ + jF] = vB;
        } else {
            pg_l[nA][jF - 192] = vA;
            pg_l[nB][jF - 192] = vB;
        }
    }
    __syncthreads();
    if (t < 512) {
        const int n = t >> 7, k = t & 127;
        if (k < 96) {
            const float* R = rt_l[n];
            float c0 = pg_l[n][k]       - R[9];
            float c1 = pg_l[n][96 + k]  - R[10];
            float c2 = pg_l[n][192 + k] - R[11];
            float r0 = R[0] * c0 + R[3] * c1 + R[6] * c2;
            float r1 = R[1] * c0 + R[4] * c1 + R[7] * c2;
            float r2 = R[2] * c0 + R[5] * c1 + R[8] * c2;
            size_t base = (size_t)(n0 + n) * DOUT_;
            fin[base + 192 + k] = r0;
            fin[base + 288 + k] = r1;
            fin[base + 384 + k] = r2;
            fin[base + 480 + k] = sqrtf(1e-8f + r0 * r0 + r1 * r1 + r2 * r2);
        }
    }
}

// ---------------- K5: out partials, split-K over 4 chunks of 528 ----------------
__global__ __launch_bounds__(256) void k_out(
    const float* __restrict__ fin, const float* __restrict__ wo,
    float* __restrict__ pout)
{
    __shared__ float a_l[64 * 52];
    __shared__ float b_l[48 * 68];
    const int t = threadIdx.x;
    const int m0 = blockIdx.x * 64, n0 = blockIdx.y * 64, kc = blockIdx.z;
    const int tx = t & 15, ty = t >> 4;
    float acc[4][4] = {};
    for (int k0 = kc * 528; k0 < kc * 528 + 528; k0 += 48) {
        #pragma unroll
        for (int e = 0; e < 3; ++e) {
            int idx = t + 256 * e;
            int r = idx / 12, c4 = (idx % 12) * 4;
            *(float4*)&a_l[r * 52 + c4] = *(const float4*)&fin[(size_t)(m0 + r) * DOUT_ + k0 + c4];
        }
        #pragma unroll
        for (int e = 0; e < 3; ++e) {
            int idx = t + 256 * e;
            int r = idx >> 4, c4 = (idx & 15) * 4;
            *(float4*)&b_l[r * 68 + c4] = *(const float4*)&wo[(size_t)(k0 + r) * 384 + n0 + c4];
        }
        __syncthreads();
        #pragma unroll 4
        for (int k = 0; k < 48; ++k) {
            float4 bv = *(const float4*)&b_l[k * 68 + tx * 4];
            #pragma unroll
            for (int i = 0; i < 4; ++i) {
                float av = a_l[(ty * 4 + i) * 52 + k];
                acc[i][0] += av * bv.x; acc[i][1] += av * bv.y;
                acc[i][2] += av * bv.z; acc[i][3] += av * bv.w;
            }
        }
        __syncthreads();
    }
    float* pr = pout + (size_t)kc * 393216;
    #pragma unroll
    for (int i = 0; i < 4; ++i) {
        float4 o;
        o.x = acc[i][0]; o.y = acc[i][1]; o.z = acc[i][2]; o.w = acc[i][3];
        *(float4*)&pr[(size_t)(m0 + ty * 4 + i) * 384 + n0 + tx * 4] = o;
    }
}

// ---------------- K6: sum split-K partials + bias ----------------
__global__ __launch_bounds__(256) void k_fin(
    const float* __restrict__ pout, const float* __restrict__ bo, float* __restrict__ out)
{
    int idx = blockIdx.x * 256 + threadIdx.x;
    float4 a = *(const float4*)&pout[(size_t)idx * 4];
    float4 b = *(const float4*)&pout[393216 + (size_t)idx * 4];
    float4 c = *(const float4*)&pout[786432 + (size_t)idx * 4];
    float4 d = *(const float4*)&pout[1179648 + (size_t)idx * 4];
    float4 bias = *(const float4*)&bo[(idx % 96) * 4];
    float4 o;
    o.x = a.x + b.x + c.x + d.x + bias.x;
    o.y = a.y + b.y + c.y + d.y + bias.y;
    o.z = a.z + b.z + c.z + d.z + bias.z;
    o.w = a.w + b.w + c.w + d.w + bias.w;
    *(float4*)&out[(size_t)idx * 4] = o;
}

extern "C" void kernel_launch(void* const* d_in, const int* in_sizes, int n_in,
                              void* d_out, int out_size, void* d_ws, size_t ws_size,
                              hipStream_t stream) {
    const float* in1   = (const float*)d_in[0];
    const float* x2d   = (const float*)d_in[1];
    const float* mask  = (const float*)d_in[2];
    const float* rotm  = (const float*)d_in[3];
    const float* trans = (const float*)d_in[4];
    const float* wq    = (const float*)d_in[5];
    const float* bq    = (const float*)d_in[6];
    const float* wkv   = (const float*)d_in[7];
    const float* bkv   = (const float*)d_in[8];
    const float* wqp   = (const float*)d_in[9];
    const float* bqp   = (const float*)d_in[10];
    const float* wkvp  = (const float*)d_in[11];
    const float* bkvp  = (const float*)d_in[12];
    const float* w2d   = (const float*)d_in[13];
    const float* b2d   = (const float*)d_in[14];
    const float* tpw   = (const float*)d_in[15];
    const float* wo    = (const float*)d_in[16];
    const float* bo    = (const float*)d_in[17];
    float* out = (float*)d_out;

    float* ws = (float*)d_ws;
    float* yraw   = ws;                    // 1,179,648
    float* qp_arr = yraw + 1179648;        //   147,456
    float* kpack  = qp_arr + 147456;       //   360,448
    float* vpack  = kpack + 360448;        //   491,520
    float* sq_arr = vpack + 491520;        //    12,288
    float* fin    = sq_arr + 12288;        // 2,162,688
    float* pout   = fin + 2162688;         // 1,572,864

    hipLaunchKernelGGL(k_gemm1, dim3(16, 18), dim3(256), 0, stream,
        in1, wq, bq, wkv, bkv, wqp, bqp, wkvp, bkvp, yraw);
    hipLaunchKernelGGL(k_rot, dim3(256), dim3(256), 0, stream,
        yraw, rotm, trans, qp_arr, kpack, vpack, sq_arr);
    hipLaunchKernelGGL(k_attn3, dim3(256), dim3(1024), 0, stream,
        x2d, mask, w2d, b2d, tpw, yraw, qp_arr, kpack, vpack, sq_arr, rotm, trans, fin);
    hipLaunchKernelGGL(k_out, dim3(16, 6, 4), dim3(256), 0, stream, fin, wo, pout);
    hipLaunchKernelGGL(k_fin, dim3(384), dim3(256), 0, stream, pout, bo, out);
}

// Round 4
// 1145.776 us; speedup vs baseline: 1.0720x; 1.0720x over previous
//
#include <hip/hip_runtime.h>
#include <math.h>

#define NN_ 1024
#define DOUT_ 2112
#define NOUT_ 384
#define G_ 4
#define MT_ 32
#define NTILES_ 32

// ---------------- K1: yraw[1024][1152] = in1 @ [wq|wkv|wqp|wkvp] + bias ----------------
__global__ __launch_bounds__(256) void k_gemm1(
    const float* __restrict__ in1,
    const float* __restrict__ wq, const float* __restrict__ bq,
    const float* __restrict__ wkv, const float* __restrict__ bkv,
    const float* __restrict__ wqp, const float* __restrict__ bqp,
    const float* __restrict__ wkvp, const float* __restrict__ bkvp,
    float* __restrict__ yraw)
{
    __shared__ float a_l[64 * 36];
    __shared__ float b_l[32 * 68];
    const int t = threadIdx.x;
    const int m0 = blockIdx.x * 64, j0 = blockIdx.y * 64;
    const int tx = t & 15, ty = t >> 4;
    float acc[4][4] = {};
    for (int k0 = 0; k0 < 384; k0 += 32) {
        #pragma unroll
        for (int e = 0; e < 2; ++e) {
            int idx = t + 256 * e;
            int r = idx >> 3, c4 = (idx & 7) * 4;
            *(float4*)&a_l[r * 36 + c4] = *(const float4*)&in1[(size_t)(m0 + r) * 384 + k0 + c4];
        }
        #pragma unroll
        for (int e = 0; e < 2; ++e) {
            int idx = t + 256 * e;
            int r = idx >> 4, c4 = (idx & 15) * 4;
            int j = j0 + c4;
            const float* w; int ncol, jj;
            if (j < 192)      { w = wq;   ncol = 192; jj = j; }
            else if (j < 576) { w = wkv;  ncol = 384; jj = j - 192; }
            else if (j < 720) { w = wqp;  ncol = 144; jj = j - 576; }
            else              { w = wkvp; ncol = 432; jj = j - 720; }
            *(float4*)&b_l[r * 68 + c4] = *(const float4*)&w[(size_t)(k0 + r) * ncol + jj];
        }
        __syncthreads();
        #pragma unroll 8
        for (int k = 0; k < 32; ++k) {
            float4 bv = *(const float4*)&b_l[k * 68 + tx * 4];
            #pragma unroll
            for (int i = 0; i < 4; ++i) {
                float av = a_l[(ty * 4 + i) * 36 + k];
                acc[i][0] += av * bv.x; acc[i][1] += av * bv.y;
                acc[i][2] += av * bv.z; acc[i][3] += av * bv.w;
            }
        }
        __syncthreads();
    }
    int j = j0 + tx * 4;
    float4 bias;
    {
        const float* b; int jj;
        if (j < 192)      { b = bq;   jj = j; }
        else if (j < 576) { b = bkv;  jj = j - 192; }
        else if (j < 720) { b = bqp;  jj = j - 576; }
        else              { b = bkvp; jj = j - 720; }
        bias = *(const float4*)&b[jj];
    }
    #pragma unroll
    for (int i = 0; i < 4; ++i) {
        float4 o;
        o.x = acc[i][0] + bias.x; o.y = acc[i][1] + bias.y;
        o.z = acc[i][2] + bias.z; o.w = acc[i][3] + bias.w;
        *(float4*)&yraw[(size_t)(m0 + ty * 4 + i) * 1152 + j] = o;
    }
}

// ---------------- K2: rotations + packing ----------------
// kpack[n][352]: [0:192 ks(h*16+s)] [192:336 kp(a*48+h*4+p)] [336:348 sk(h)]
// vpack[n][480]: [0:192 vs(h*16+s)] [192:480 vp(a*96+h*8+p)]
__global__ __launch_bounds__(256) void k_rot(
    const float* __restrict__ yraw, const float* __restrict__ rotm, const float* __restrict__ trans,
    float* __restrict__ qp_arr, float* __restrict__ kpack, float* __restrict__ vpack,
    float* __restrict__ sq_arr)
{
    __shared__ float rt_l[4][12];
    const int t = threadIdx.x;
    const int n0 = blockIdx.x * 4;
    if (t < 48) {
        int n_ = t / 12, i = t % 12;
        rt_l[n_][i] = (i < 9) ? rotm[(n0 + n_) * 9 + i] : trans[(n0 + n_) * 3 + (i - 9)];
    }
    __syncthreads();
    const int n_ = t >> 6, l = t & 63;
    const int n = n0 + n_;
    const float* y = yraw + (size_t)n * 1152;
    const float* R = rt_l[n_];
    #pragma unroll
    for (int jj = 0; jj < 9; ++jj) {
        int o = l + 64 * jj;
        if (o < 144) {
            int a = o / 48, kk = o % 48;
            float v = R[9 + a] + R[a*3+0] * y[576 + kk] + R[a*3+1] * y[576 + 48 + kk] + R[a*3+2] * y[576 + 96 + kk];
            qp_arr[(size_t)n * 144 + o] = v;
        } else if (o < 288) {
            int o2 = o - 144;
            int a = o2 / 48, r2 = o2 % 48;
            int kk = (r2 >> 2) * 12 + (r2 & 3);
            float v = R[9 + a] + R[a*3+0] * y[720 + kk] + R[a*3+1] * y[720 + 144 + kk] + R[a*3+2] * y[720 + 288 + kk];
            kpack[(size_t)n * 352 + 192 + o2] = v;
        } else {
            int o3 = o - 288;
            int a = o3 / 96, r2 = o3 % 96;
            int kk = (r2 >> 3) * 12 + 4 + (r2 & 7);
            float v = R[9 + a] + R[a*3+0] * y[720 + kk] + R[a*3+1] * y[720 + 144 + kk] + R[a*3+2] * y[720 + 288 + kk];
            vpack[(size_t)n * 480 + 192 + o3] = v;
        }
    }
    #pragma unroll
    for (int jj = 0; jj < 3; ++jj) {
        int o = l + 64 * jj;  // 0..191
        int h = o >> 4, r2 = o & 15;
        kpack[(size_t)n * 352 + o] = y[192 + h * 32 + r2];
        vpack[(size_t)n * 480 + o] = y[192 + h * 32 + 16 + r2];
    }
    if (l < 24) {
        int which = l / 12, h = l % 12;
        int base = (which == 0) ? 576 : 720;
        int stride = (which == 0) ? 48 : 144;
        float s = 0.f;
        #pragma unroll
        for (int a = 0; a < 3; ++a) {
            #pragma unroll
            for (int p = 0; p < 4; ++p) {
                int kk = (which == 0) ? (h * 4 + p) : (h * 12 + p);
                float v = R[9 + a] + R[a*3+0] * y[base + kk] + R[a*3+1] * y[base + stride + kk] + R[a*3+2] * y[base + 2 * stride + kk];
                s += v * v;
            }
        }
        if (which == 0) sq_arr[(size_t)n * 12 + h] = s;
        else            kpack[(size_t)n * 352 + 336 + h] = s;
    }
}

// ---------------- K3: fused flash IPA, 4 query rows per block, 1024 threads ----------------
__global__ __launch_bounds__(1024, 4) void k_attn3(
    const float* __restrict__ x2d, const float* __restrict__ mask,
    const float* __restrict__ w2d, const float* __restrict__ b2d, const float* __restrict__ tpw,
    const float* __restrict__ yraw, const float* __restrict__ qp_arr,
    const float* __restrict__ kpack, const float* __restrict__ vpack,
    const float* __restrict__ sq_arr, const float* __restrict__ rotm,
    const float* __restrict__ trans,
    float* __restrict__ fin)
{
    __shared__ float K_l[MT_][356];          // 45.6 KB
    __shared__ float x_l[G_][MT_][132];      // 67.6 KB
    __shared__ float tl[G_][12][36];         // 6.9 KB
    __shared__ float at2_l[G_][MT_][13];     // 6.7 KB (13: coprime w/ 32 banks)
    __shared__ float w2_l[12][128];          // 6.1 KB
    __shared__ float qs_l[G_][192];
    __shared__ float qp_l[G_][144];
    __shared__ float sq_l[G_][12];
    __shared__ float rt_l[G_][12];
    __shared__ float pw_l[12], b2_l[12];
    __shared__ float maskn_l[G_];
    __shared__ float rmax_l[G_][12], rsum_l[G_][12], alph_l[G_][12];
    __shared__ float pg_l[G_][288];

    const int t = threadIdx.x;
    const int n0 = blockIdx.x * G_;

    // ---- thread mappings ----
    const int sn = t >> 8;             // stage: n
    const int sm = (t >> 3) & 31;      // stage: m
    const int k8 = t & 7;              // stage: k-octant (16 c each)
    const int rep = t >> 9;            // logits: n-pair select
    const int hx  = (t >> 5) & 15;     // logits: h (active <12)
    const int m2  = t & 31;            // logits: m
    const int cq  = t & 31;            // res2d: c-quad
    const int hg5 = (t >> 5) & 3;      // res2d: h-trio
    const int n5  = (t >> 7) & 3;      // res2d: n
    const int ms  = t >> 9;            // res2d: m-half
    const int hb  = hg5 * 3;
    const int jF  = t >> 1;            // resF: j (active t<960)
    const int npF = t & 1;             // resF: n-pair
    const int hF  = (jF < 192) ? (jF >> 4) : (((jF - 192) % 96) >> 3);

    float accR[12];
    #pragma unroll
    for (int e = 0; e < 12; ++e) accR[e] = 0.f;
    float accF0 = 0.f, accF1 = 0.f;
    float4 xpf[4];

    // ---- prologue ----
    for (int i = t; i < 1536; i += 1024) { int c = i / 12, h = i % 12; w2_l[h][c] = w2d[i]; }
    if (t < 768) { int nl = t / 192, r = t % 192; qs_l[nl][r] = yraw[(size_t)(n0 + nl) * 1152 + r]; }
    if (t < 576) { int nl = t / 144, r = t % 144; qp_l[nl][r] = qp_arr[(size_t)(n0 + nl) * 144 + r]; }
    if (t < 48)  { int nl = t / 12, r = t % 12; sq_l[nl][r] = sq_arr[(size_t)(n0 + nl) * 12 + r]; }
    if (t >= 64 && t < 112) {
        int i = t - 64, nl = i / 12, r = i % 12;
        rt_l[nl][r] = (r < 9) ? rotm[(n0 + nl) * 9 + r] : trans[(n0 + nl) * 3 + (r - 9)];
    }
    if (t >= 128 && t < 140) pw_l[t - 128] = 0.13608276348795434f * log1pf(__expf(tpw[t - 128]));
    if (t >= 160 && t < 172) b2_l[t - 160] = b2d[t - 160];
    if (t >= 192 && t < 196) maskn_l[t - 192] = mask[n0 + (t - 192)];
    if (t >= 224 && t < 272) { int i = t - 224; rmax_l[i / 12][i % 12] = -3.0e38f; }
    if (t >= 288 && t < 336) { int i = t - 288; rsum_l[i / 12][i % 12] = 0.f; }

    // initial x prefetch (tile 0)
    #pragma unroll
    for (int f = 0; f < 4; ++f)
        xpf[f] = *(const float4*)&x2d[((size_t)(n0 + sn) * NN_ + sm) * 128 + k8 * 16 + f * 4];
    __syncthreads();

    for (int mt = 0; mt < NTILES_; ++mt) {
        const int m0 = mt * MT_;
        // ================= P1: stage K (L2/L3-hit) + commit x prefetch + att2d =================
        {
            // issue K loads first; at2 compute below (independent) hides their latency
            const float* kb = kpack + (size_t)m0 * 352;
            float4 k0v = *(const float4*)&kb[(size_t)t * 4];
            float4 k1v = *(const float4*)&kb[(size_t)(t + 1024) * 4];
            float4 k2v;
            int fi = (t < 768) ? (t + 2048) : 0;
            k2v = *(const float4*)&kb[(size_t)fi * 4];
            #pragma unroll
            for (int f = 0; f < 4; ++f)
                *(float4*)&x_l[sn][sm][k8 * 16 + f * 4] = xpf[f];
            float at2[12];
            #pragma unroll
            for (int h = 0; h < 12; ++h) {
                float s = 0.f;
                #pragma unroll
                for (int f = 0; f < 4; ++f) {
                    float4 wv = *(const float4*)&w2_l[h][k8 * 16 + f * 4];
                    s += xpf[f].x * wv.x + xpf[f].y * wv.y + xpf[f].z * wv.z + xpf[f].w * wv.w;
                }
                at2[h] = s;
            }
            #pragma unroll
            for (int d = 1; d <= 4; d <<= 1) {
                #pragma unroll
                for (int h = 0; h < 12; ++h) at2[h] += __shfl_xor(at2[h], d);
            }
            if (k8 == 0) {
                #pragma unroll
                for (int h = 0; h < 12; ++h) at2_l[sn][sm][h] = at2[h];
            }
            *(float4*)&K_l[t / 88][(t % 88) * 4] = k0v;
            *(float4*)&K_l[(t + 1024) / 88][((t + 1024) % 88) * 4] = k1v;
            if (t < 768) *(float4*)&K_l[(t + 2048) / 88][((t + 2048) % 88) * 4] = k2v;
        }
        __syncthreads();

        // ================= P2: logits + online softmax (wave-internal) =================
        if (hx < 12) {
            const int h = hx;
            const float* kr = &K_l[m2][0];
            float4 ksA = *(const float4*)&kr[h * 16 + 0];
            float4 ksB = *(const float4*)&kr[h * 16 + 4];
            float4 ksC = *(const float4*)&kr[h * 16 + 8];
            float4 ksD = *(const float4*)&kr[h * 16 + 12];
            float4 kpA = *(const float4*)&kr[192 + h * 4];
            float4 kpB = *(const float4*)&kr[192 + 48 + h * 4];
            float4 kpC = *(const float4*)&kr[192 + 96 + h * 4];
            float skm = kr[336 + h];
            float mkm = mask[m0 + m2];
            float pwh = pw_l[h];
            #pragma unroll
            for (int nn = 0; nn < 2; ++nn) {
                const int n = rep * 2 + nn;
                const float4* qsn = (const float4*)&qs_l[n][h * 16];
                float dqs = qsn[0].x*ksA.x + qsn[0].y*ksA.y + qsn[0].z*ksA.z + qsn[0].w*ksA.w
                          + qsn[1].x*ksB.x + qsn[1].y*ksB.y + qsn[1].z*ksB.z + qsn[1].w*ksB.w
                          + qsn[2].x*ksC.x + qsn[2].y*ksC.y + qsn[2].z*ksC.z + qsn[2].w*ksC.w
                          + qsn[3].x*ksD.x + qsn[3].y*ksD.y + qsn[3].z*ksD.z + qsn[3].w*ksD.w;
                float4 qA = *(const float4*)&qp_l[n][h * 4];
                float4 qB = *(const float4*)&qp_l[n][48 + h * 4];
                float4 qC = *(const float4*)&qp_l[n][96 + h * 4];
                float qk = qA.x*kpA.x + qA.y*kpA.y + qA.z*kpA.z + qA.w*kpA.w
                         + qB.x*kpB.x + qB.y*kpB.y + qB.z*kpB.z + qB.w*kpB.w
                         + qC.x*kpC.x + qC.y*kpC.y + qC.z*kpC.z + qC.w*kpC.w;
                float lg = 0.14433756729740643f * dqs
                         + pwh * qk - 0.5f * pwh * (sq_l[n][h] + skm)
                         + 0.57735026918962576f * (at2_l[n][m2][h] + b2_l[h])
                         - 100000.0f * (1.0f - maskn_l[n] * mkm);
                float tm = lg;
                tm = fmaxf(tm, __shfl_xor(tm, 1));
                tm = fmaxf(tm, __shfl_xor(tm, 2));
                tm = fmaxf(tm, __shfl_xor(tm, 4));
                tm = fmaxf(tm, __shfl_xor(tm, 8));
                tm = fmaxf(tm, __shfl_xor(tm, 16));
                float om = rmax_l[n][h];
                float nm = fmaxf(om, tm);
                float p = __expf(lg - nm);
                tl[n][h][m2] = p;
                float ps = p;
                ps += __shfl_xor(ps, 1);
                ps += __shfl_xor(ps, 2);
                ps += __shfl_xor(ps, 4);
                ps += __shfl_xor(ps, 8);
                ps += __shfl_xor(ps, 16);
                if (m2 == 0) {
                    float al = __expf(om - nm);
                    rmax_l[n][h] = nm;
                    alph_l[n][h] = al;
                    rsum_l[n][h] = rsum_l[n][h] * al + ps;
                }
            }
        }
        __syncthreads();

        // ================= P5: prefetch-next-x + rescale + res2d; P6: resF =================
        {
            int m1 = (mt + 1 == NTILES_) ? 0 : (m0 + MT_);
            #pragma unroll
            for (int f = 0; f < 4; ++f)
                xpf[f] = *(const float4*)&x2d[((size_t)(n0 + sn) * NN_ + m1 + sm) * 128 + k8 * 16 + f * 4];
        }
        {
            float alv[3];
            #pragma unroll
            for (int e = 0; e < 3; ++e) alv[e] = alph_l[n5][hb + e];
            #pragma unroll
            for (int e = 0; e < 12; ++e) accR[e] *= alv[e >> 2];
            #pragma unroll
            for (int mm = 0; mm < 16; mm += 4) {
                const int mB = ms * 16 + mm;
                float4 p0 = *(const float4*)&tl[n5][hb + 0][mB];
                float4 p1 = *(const float4*)&tl[n5][hb + 1][mB];
                float4 p2 = *(const float4*)&tl[n5][hb + 2][mB];
                float pa0[4] = {p0.x, p0.y, p0.z, p0.w};
                float pa1[4] = {p1.x, p1.y, p1.z, p1.w};
                float pa2[4] = {p2.x, p2.y, p2.z, p2.w};
                #pragma unroll
                for (int q = 0; q < 4; ++q) {
                    float4 xv = *(const float4*)&x_l[n5][mB + q][cq * 4];
                    accR[0] += pa0[q] * xv.x; accR[1]  += pa0[q] * xv.y; accR[2]  += pa0[q] * xv.z; accR[3]  += pa0[q] * xv.w;
                    accR[4] += pa1[q] * xv.x; accR[5]  += pa1[q] * xv.y; accR[6]  += pa1[q] * xv.z; accR[7]  += pa1[q] * xv.w;
                    accR[8] += pa2[q] * xv.x; accR[9]  += pa2[q] * xv.y; accR[10] += pa2[q] * xv.z; accR[11] += pa2[q] * xv.w;
                }
            }
        }
        if (t < 960) {
            const int nA = npF * 2, nB = nA + 1;
            accF0 *= alph_l[nA][hF];
            accF1 *= alph_l[nB][hF];
            const float* vb = vpack + (size_t)m0 * 480 + jF;
            #pragma unroll 2
            for (int mm = 0; mm < 32; mm += 4) {
                float4 pA = *(const float4*)&tl[nA][hF][mm];
                float4 pB = *(const float4*)&tl[nB][hF][mm];
                float v0 = vb[(size_t)(mm + 0) * 480];
                float v1 = vb[(size_t)(mm + 1) * 480];
                float v2 = vb[(size_t)(mm + 2) * 480];
                float v3 = vb[(size_t)(mm + 3) * 480];
                accF0 += pA.x * v0 + pA.y * v1 + pA.z * v2 + pA.w * v3;
                accF1 += pB.x * v0 + pB.y * v1 + pB.z * v2 + pB.w * v3;
            }
        }
        __syncthreads();
    }

    // ================= epilogue =================
    float* red = &K_l[0][0];
    if (ms == 1) {
        #pragma unroll
        for (int e = 0; e < 12; ++e) red[(t & 511) * 12 + e] = accR[e];
    }
    __syncthreads();
    if (ms == 0) {
        float inv[3];
        #pragma unroll
        for (int e = 0; e < 3; ++e) inv[e] = 1.f / rsum_l[n5][hb + e];
        #pragma unroll
        for (int e = 0; e < 12; ++e) {
            float v = (accR[e] + red[(t & 511) * 12 + e]) * inv[e >> 2];
            fin[(size_t)(n0 + n5) * DOUT_ + 576 + (size_t)(hb + (e >> 2)) * 128 + cq * 4 + (e & 3)] = v;
        }
    }
    if (t < 960) {
        const int nA = npF * 2, nB = nA + 1;
        float vA = accF0 / rsum_l[nA][hF];
        float vB = accF1 / rsum_l[nB][hF];
        if (jF < 192) {
            fin[(size_t)(n0 + nA) * DOUT_ + jF] = vA;
            fin[(size_t)(n0 + nB) * DOUT_ + jF] = vB;
        } else {
            pg_l[nA][jF - 192] = vA;
            pg_l[nB][jF - 192] = vB;
        }
    }
    __syncthreads();
    if (t < 512) {
        const int n = t >> 7, k = t & 127;
        if (k < 96) {
            const float* R = rt_l[n];
            float c0 = pg_l[n][k]       - R[9];
            float c1 = pg_l[n][96 + k]  - R[10];
            float c2 = pg_l[n][192 + k] - R[11];
            float r0 = R[0] * c0 + R[3] * c1 + R[6] * c2;
            float r1 = R[1] * c0 + R[4] * c1 + R[7] * c2;
            float r2 = R[2] * c0 + R[5] * c1 + R[8] * c2;
            size_t base = (size_t)(n0 + n) * DOUT_;
            fin[base + 192 + k] = r0;
            fin[base + 288 + k] = r1;
            fin[base + 384 + k] = r2;
            fin[base + 480 + k] = sqrtf(1e-8f + r0 * r0 + r1 * r1 + r2 * r2);
        }
    }
}

// ---------------- K5: out partials, split-K over 4 chunks of 528 ----------------
__global__ __launch_bounds__(256) void k_out(
    const float* __restrict__ fin, const float* __restrict__ wo,
    float* __restrict__ pout)
{
    __shared__ float a_l[64 * 52];
    __shared__ float b_l[48 * 68];
    const int t = threadIdx.x;
    const int m0 = blockIdx.x * 64, n0 = blockIdx.y * 64, kc = blockIdx.z;
    const int tx = t & 15, ty = t >> 4;
    float acc[4][4] = {};
    for (int k0 = kc * 528; k0 < kc * 528 + 528; k0 += 48) {
        #pragma unroll
        for (int e = 0; e < 3; ++e) {
            int idx = t + 256 * e;
            int r = idx / 12, c4 = (idx % 12) * 4;
            *(float4*)&a_l[r * 52 + c4] = *(const float4*)&fin[(size_t)(m0 + r) * DOUT_ + k0 + c4];
        }
        #pragma unroll
        for (int e = 0; e < 3; ++e) {
            int idx = t + 256 * e;
            int r = idx >> 4, c4 = (idx & 15) * 4;
            *(float4*)&b_l[r * 68 + c4] = *(const float4*)&wo[(size_t)(k0 + r) * 384 + n0 + c4];
        }
        __syncthreads();
        #pragma unroll 4
        for (int k = 0; k < 48; ++k) {
            float4 bv = *(const float4*)&b_l[k * 68 + tx * 4];
            #pragma unroll
            for (int i = 0; i < 4; ++i) {
                float av = a_l[(ty * 4 + i) * 52 + k];
                acc[i][0] += av * bv.x; acc[i][1] += av * bv.y;
                acc[i][2] += av * bv.z; acc[i][3] += av * bv.w;
            }
        }
        __syncthreads();
    }
    float* pr = pout + (size_t)kc * 393216;
    #pragma unroll
    for (int i = 0; i < 4; ++i) {
        float4 o;
        o.x = acc[i][0]; o.y = acc[i][1]; o.z = acc[i][2]; o.w = acc[i][3];
        *(float4*)&pr[(size_t)(m0 + ty * 4 + i) * 384 + n0 + tx * 4] = o;
    }
}

// ---------------- K6: sum split-K partials + bias ----------------
__global__ __launch_bounds__(256) void k_fin(
    const float* __restrict__ pout, const float* __restrict__ bo, float* __restrict__ out)
{
    int idx = blockIdx.x * 256 + threadIdx.x;
    float4 a = *(const float4*)&pout[(size_t)idx * 4];
    float4 b = *(const float4*)&pout[393216 + (size_t)idx * 4];
    float4 c = *(const float4*)&pout[786432 + (size_t)idx * 4];
    float4 d = *(const float4*)&pout[1179648 + (size_t)idx * 4];
    float4 bias = *(const float4*)&bo[(idx % 96) * 4];
    float4 o;
    o.x = a.x + b.x + c.x + d.x + bias.x;
    o.y = a.y + b.y + c.y + d.y + bias.y;
    o.z = a.z + b.z + c.z + d.z + bias.z;
    o.w = a.w + b.w + c.w + d.w + bias.w;
    *(float4*)&out[(size_t)idx * 4] = o;
}

extern "C" void kernel_launch(void* const* d_in, const int* in_sizes, int n_in,
                              void* d_out, int out_size, void* d_ws, size_t ws_size,
                              hipStream_t stream) {
    const float* in1   = (const float*)d_in[0];
    const float* x2d   = (const float*)d_in[1];
    const float* mask  = (const float*)d_in[2];
    const float* rotm  = (const float*)d_in[3];
    const float* trans = (const float*)d_in[4];
    const float* wq    = (const float*)d_in[5];
    const float* bq    = (const float*)d_in[6];
    const float* wkv   = (const float*)d_in[7];
    const float* bkv   = (const float*)d_in[8];
    const float* wqp   = (const float*)d_in[9];
    const float* bqp   = (const float*)d_in[10];
    const float* wkvp  = (const float*)d_in[11];
    const float* bkvp  = (const float*)d_in[12];
    const float* w2d   = (const float*)d_in[13];
    const float* b2d   = (const float*)d_in[14];
    const float* tpw   = (const float*)d_in[15];
    const float* wo    = (const float*)d_in[16];
    const float* bo    = (const float*)d_in[17];
    float* out = (float*)d_out;

    float* ws = (float*)d_ws;
    float* yraw   = ws;                    // 1,179,648
    float* qp_arr = yraw + 1179648;        //   147,456
    float* kpack  = qp_arr + 147456;       //   360,448
    float* vpack  = kpack + 360448;        //   491,520
    float* sq_arr = vpack + 491520;        //    12,288
    float* fin    = sq_arr + 12288;        // 2,162,688
    float* pout   = fin + 2162688;         // 1,572,864

    hipLaunchKernelGGL(k_gemm1, dim3(16, 18), dim3(256), 0, stream,
        in1, wq, bq, wkv, bkv, wqp, bqp, wkvp, bkvp, yraw);
    hipLaunchKernelGGL(k_rot, dim3(256), dim3(256), 0, stream,
        yraw, rotm, trans, qp_arr, kpack, vpack, sq_arr);
    hipLaunchKernelGGL(k_attn3, dim3(256), dim3(1024), 0, stream,
        x2d, mask, w2d, b2d, tpw, yraw, qp_arr, kpack, vpack, sq_arr, rotm, trans, fin);
    hipLaunchKernelGGL(k_out, dim3(16, 6, 4), dim3(256), 0, stream, fin, wo, pout);
    hipLaunchKernelGGL(k_fin, dim3(384), dim3(256), 0, stream, pout, bo, out);
}